// Round 17
// baseline (78.175 us; speedup 1.0000x reference)
//
#include <hip/hip_runtime.h>
#include <stdint.h>

// ---------------- problem constants ----------------
#define B_ROWS 16384
#define NF 26
#define NV 100000
#define ND 13
#define NH 400
#define XPAD 448     // GEMM1 K padded (14 tiles of 32)
#define ZPAD 416     // GEMM2 K padded (13 tiles of 32)
#define EPS 1e-5f

typedef __attribute__((ext_vector_type(8))) short short8;
typedef __attribute__((ext_vector_type(4))) float f32x4;
typedef __attribute__((ext_vector_type(4))) unsigned int uint4v;

__device__ inline float bf2f(unsigned short u) {
    union { unsigned int i; float f; } v; v.i = (unsigned int)u << 16; return v.f;
}
__device__ inline unsigned short f2bf(float f) {
    union { float f; unsigned int i; } v; v.f = f;
    return (unsigned short)((v.i + 0x7fff + ((v.i >> 16) & 1)) >> 16);
}

// direct global->LDS DMA; one call = 64 lanes x 16B = 1024B at dest base
typedef __attribute__((address_space(1))) const unsigned int g_u32;
typedef __attribute__((address_space(3))) unsigned int l_u32;
__device__ __forceinline__ void gload_lds16(const void* g, void* l) {
    __builtin_amdgcn_global_load_lds((g_u32*)g, (l_u32*)l, 16, 0, 0);
}

// ---------------- ws layout (bytes) ----------------
#define X_OFF    0
#define Z1_OFF   14680064
#define Z2_OFF   28311552
#define W1S_OFF  41943040
#define W2S_OFF  42344448
#define FM1V_OFF 42717184
#define ST_OFF   44421120

// =====================================================================
// gather_prep v2: grid 1917 blocks x 256.
// blocks 0..1663   : field-partitioned gather, XCD-pinned (bid&7 == f%8):
//                    X[r][f*16+k] = bf16(emb[f][idx][k]); fm1v[f][r] = fm1[f][idx]
// blocks 1664..1852: W1s/W2s staging (+ st zero in first)
// blocks 1853..1916: X dense cols 416..447 (Xd | zeros)
// =====================================================================
__global__ __launch_bounds__(256) void gather_prep(
    const int* __restrict__ Xcat, const float* __restrict__ Xdense,
    const float* __restrict__ fm1, const float* __restrict__ emb,
    const float* __restrict__ W1, const float* __restrict__ W2,
    unsigned short* __restrict__ X, float* __restrict__ fm1v,
    unsigned short* __restrict__ W1s, unsigned short* __restrict__ W2s,
    float* __restrict__ st)
{
    const int tid = threadIdx.x;
    const int bid = blockIdx.x;
    if (bid >= 1853) {
        // ---------- dense-X path ----------
        int r = (bid - 1853) * 256 + tid;        // 0..16383 exact
        unsigned short o[32];
        #pragma unroll
        for (int j = 0; j < 32; ++j) {
            float v = (j < ND) ? Xdense[(size_t)r * ND + j] : 0.f;
            o[j] = f2bf(v);
        }
        uint4v* dst = (uint4v*)(X + (size_t)r * XPAD + 416);
        dst[0] = *(uint4v*)&o[0];
        dst[1] = *(uint4v*)&o[8];
        dst[2] = *(uint4v*)&o[16];
        dst[3] = *(uint4v*)&o[24];
        return;
    }
    if (bid >= 1664) {
        // ---------- W prep path ----------
        if (bid == 1664) {
            for (int i = tid; i < 6656; i += 256) st[i] = 0.f;  // 4 replicas
        }
        int c = (bid - 1664) * 256 + tid;        // 0..48383
        const float* W; unsigned short* dst; int K; int cc;
        if (c < 25088) { W = W1; dst = W1s; K = 429; cc = c; }
        else           { W = W2; dst = W2s; K = 400; cc = c - 25088; }
        int n  = cc % 448;
        int q  = (cc / 448) & 3;
        int kt = cc / 1792;
        unsigned short o[8];
        #pragma unroll
        for (int j = 0; j < 8; ++j) {
            int k = kt * 32 + q * 8 + j;
            float v = (n < NH && k < K) ? W[(size_t)k * NH + n] : 0.f;
            o[j] = f2bf(v);
        }
        *(uint4v*)(dst + (size_t)cc * 8) = *(uint4v*)o;
        return;
    }
    // ---------- gather path (XCD-pinned by field) ----------
    const int x = bid & 7;
    const int s = bid >> 3;                  // 0..207
    const int nf = (x < 2) ? 4 : 3;          // fields on this XCD
    const int nc = 208 / nf;                 // 52 or 69 chunks/field
    const int fi = s / nc;
    if (fi >= nf) return;                    // only x>=2, s==207
    const int f = x + 8 * fi;
    const int chunk = s - fi * nc;
    const int rpc = (B_ROWS + nc - 1) / nc;  // 316 or 238
    const int r0 = chunk * rpc;
    const int r1 = (r0 + rpc < B_ROWS) ? r0 + rpc : B_ROWS;

    const int k = tid & 15, rr = tid >> 4;   // 16 lanes(k) x 16 rows
    const float* et = emb + (size_t)f * NV * 16;
    const float* ft = fm1 + (size_t)f * NV;
    float* fv = fm1v + (size_t)f * B_ROWS;

    for (int r = r0 + rr; r < r1; r += 32) {     // 2 rows per thread per iter
        int rb = r + 16;
        bool okb = rb < r1;
        int idx0 = Xcat[(size_t)r * NF + f];
        int idx1 = okb ? Xcat[(size_t)rb * NF + f] : idx0;
        float v0 = et[(size_t)idx0 * 16 + k];
        float v1 = et[(size_t)idx1 * 16 + k];
        X[(size_t)r * XPAD + f * 16 + k] = f2bf(v0);
        if (okb) X[(size_t)rb * XPAD + f * 16 + k] = f2bf(v1);
        if (k == 0) {
            fv[r] = ft[idx0];
            if (okb) fv[rb] = ft[idx1];
        }
    }
}

// =====================================================================
// gemm_v5 (R16 champion, verbatim): barrier-free per-wave GEMM + T4
// counted-vmcnt double-buffered slices. grid 256 x 512.
// =====================================================================
template<int NT, int LDA, bool APPLY_BN>
__global__ __launch_bounds__(512, 2) void gemm_v5(
    const unsigned short* __restrict__ A,
    const unsigned short* __restrict__ Wst,
    const float* __restrict__ bias,
    const float* __restrict__ st_all,
    const float* __restrict__ g, const float* __restrict__ be,
    unsigned short* __restrict__ Z, int ldz, int padZ,
    float* __restrict__ st_out, int sumOff, int sqOff)
{
    __shared__ __align__(16) unsigned short slices[51200];  // 2 bufs x 25600
    __shared__ float alpha_s[416], beta_s[416];

    const int tid = threadIdx.x, bid = blockIdx.x;
    const int lane = tid & 63, wv = tid >> 6;
    const int rg = wv >> 2, w4 = wv & 3;
    const int l15 = lane & 15, qh = lane >> 4;
    const int cb = (w4 == 0) ? 0 : (112 + (w4 - 1) * 96);
    const int NFW = (w4 == 0) ? 7 : 6;
    const int soff = rg * 12800 + ((w4 == 0) ? 0 : (3584 + (w4 - 1) * 3072));
    const int arowA = bid * 64 + rg * 32 + l15;
    const int arowB = arowA + 16;

    if constexpr (APPLY_BN) {
        if (tid < 416) {
            int c = tid;
            float a = 0.f, b = 0.f;
            if (c < NH) {
                float gs = 0.f, gq = 0.f;
                #pragma unroll
                for (int cp = 0; cp < 4; ++cp) {
                    gs += st_all[cp * 1664 + c];
                    gq += st_all[cp * 1664 + 416 + c];
                }
                float mean = gs * (1.f / 16384.f);
                float var  = gq * (1.f / 16384.f) - mean * mean;
                a = g[c] * rsqrtf(var + EPS);
                b = be[c] - mean * a;
            }
            alpha_s[c] = a; beta_s[c] = b;
        }
        __syncthreads();
    }

    f32x4 acc0[7], acc1[7];
    #pragma unroll
    for (int i = 0; i < 7; ++i) { acc0[i] = f32x4{0,0,0,0}; acc1[i] = f32x4{0,0,0,0}; }

    auto stageW = [&](int kt, int buf) {
        unsigned short* sl = slices + buf * 25600 + soff;
        #pragma unroll
        for (int i = 0; i < 7; ++i) if (i < NFW) {
            int ci = (kt * 4 + qh) * 448 + cb + i * 16 + l15;
            gload_lds16(Wst + (size_t)ci * 8, sl + i * 512);
        }
    };
    auto ldA = [&](int kt, short8& a, short8& b) {
        a = *(const short8*)(A + (size_t)arowA * LDA + kt * 32 + qh * 8);
        b = *(const short8*)(A + (size_t)arowB * LDA + kt * 32 + qh * 8);
    };
    auto waitN = [&]() {
        if (w4 == 0) asm volatile("s_waitcnt vmcnt(9)" ::: "memory");
        else         asm volatile("s_waitcnt vmcnt(8)" ::: "memory");
        __builtin_amdgcn_sched_barrier(0);
    };
    auto wait0 = [&]() {
        asm volatile("s_waitcnt vmcnt(0)" ::: "memory");
        __builtin_amdgcn_sched_barrier(0);
    };
    auto waitlg = [&]() {
        asm volatile("s_waitcnt lgkmcnt(0)" ::: "memory");
        __builtin_amdgcn_sched_barrier(0);
    };

    auto phase = [&](int kt, int buf, bool last, bool issue,
                     short8& afA, short8& afB) {
        if (last) wait0(); else waitN();
        const unsigned short* sl = slices + buf * 25600 + soff;
        short8 bf[7];
        #pragma unroll
        for (int i = 0; i < 7; ++i) if (i < NFW)
            bf[i] = *(const short8*)(sl + i * 512 + lane * 8);
        short8 aA = afA, aB = afB;
        waitlg();
        if (issue) { stageW(kt + 2, buf); ldA(kt + 2, afA, afB); }
        if constexpr (APPLY_BN) {
            const int k0 = kt * 32 + qh * 8;
            #pragma unroll
            for (int j = 0; j < 8; ++j) {
                float al = alpha_s[k0 + j], bt = beta_s[k0 + j];
                aA[j] = (short)f2bf(fmaxf(0.f, al * bf2f((unsigned short)aA[j]) + bt));
                aB[j] = (short)f2bf(fmaxf(0.f, al * bf2f((unsigned short)aB[j]) + bt));
            }
        }
        #pragma unroll
        for (int i = 0; i < 7; ++i) if (i < NFW) {
            acc0[i] = __builtin_amdgcn_mfma_f32_16x16x32_bf16(aA, bf[i], acc0[i], 0, 0, 0);
            acc1[i] = __builtin_amdgcn_mfma_f32_16x16x32_bf16(aB, bf[i], acc1[i], 0, 0, 0);
        }
    };

    short8 afA0, afB0, afA1, afB1;
    stageW(0, 0); ldA(0, afA0, afB0);
    stageW(1, 1); ldA(1, afA1, afB1);

    int kt2 = 0;
    for (; kt2 + 3 < NT; kt2 += 2) {
        phase(kt2,     0, false, true, afA0, afB0);
        phase(kt2 + 1, 1, false, true, afA1, afB1);
    }
    if constexpr (NT % 2 == 0) {
        phase(NT - 2, 0, false, false, afA0, afB0);
        phase(NT - 1, 1, true,  false, afA1, afB1);
    } else {
        phase(NT - 3, 0, false, true,  afA0, afB0);
        phase(NT - 2, 1, false, false, afA1, afB1);
        phase(NT - 1, 0, true,  false, afA0, afB0);
    }

    float* stc = st_out + (bid & 3) * 1664;
    #pragma unroll
    for (int i = 0; i < 7; ++i) if (i < NFW) {
        int col = cb + i * 16 + l15;
        float bv = bias[col];
        float ps = 0.f, pq = 0.f;
        #pragma unroll
        for (int q = 0; q < 4; ++q) {
            float v0 = acc0[i][q] + bv;
            float v1 = acc1[i][q] + bv;
            Z[(size_t)(bid * 64 + rg * 32 + qh * 4 + q) * ldz + col] = f2bf(v0);
            Z[(size_t)(bid * 64 + rg * 32 + 16 + qh * 4 + q) * ldz + col] = f2bf(v1);
            ps += v0 + v1; pq += v0 * v0 + v1 * v1;
        }
        ps += __shfl_xor(ps, 16, 64); ps += __shfl_xor(ps, 32, 64);
        pq += __shfl_xor(pq, 16, 64); pq += __shfl_xor(pq, 32, 64);
        if (qh == 0) {
            atomicAdd(&stc[sumOff + col], ps);
            atomicAdd(&stc[sqOff + col], pq);
        }
    }
    if (padZ && w4 == 3) {
        #pragma unroll
        for (int rr = 0; rr < 8; ++rr)
            Z[(size_t)(bid * 64 + rg * 32 + rr * 4 + qh) * ldz + 400 + l15] = 0;
    }
}

// =====================================================================
// final_v2: Phase A computes extra[r] = FM2 + fm1v-sum + dense-dot + bd
// from X (8 threads/row, shuffle all-reduce); Phase B = BN2 + dnn dot.
// grid 512 x 256, 32 rows/block.
// =====================================================================
__global__ __launch_bounds__(256) void final_kernel(
    const unsigned short* __restrict__ Z2,
    const float* __restrict__ st_all,
    const float* __restrict__ g2, const float* __restrict__ be2,
    const float* __restrict__ W3, const float* __restrict__ b3,
    const unsigned short* __restrict__ X, const float* __restrict__ fm1v,
    const float* __restrict__ Wd, const float* __restrict__ bd,
    float* __restrict__ out)
{
    __shared__ float a2s[NH], b2s[NH], w3s[NH];
    __shared__ float extra_s[32];
    __shared__ float wd_s[16];
    int tid = threadIdx.x;
    for (int c = tid; c < NH; c += 256) {
        float gs = 0.f, gq = 0.f;
        #pragma unroll
        for (int cp = 0; cp < 4; ++cp) {
            gs += st_all[cp * 1664 + 832 + c];
            gq += st_all[cp * 1664 + 1248 + c];
        }
        float mean = gs * (1.f / 16384.f);
        float var  = gq * (1.f / 16384.f) - mean * mean;
        float a = g2[c] * rsqrtf(var + EPS);
        a2s[c] = a;
        b2s[c] = be2[c] - mean * a;
        w3s[c] = W3[c];
    }
    if (tid < 16) wd_s[tid] = (tid < ND) ? Wd[tid] : 0.f;
    __syncthreads();

    // ---------- Phase A: FM terms per row ----------
    {
        int rloc = tid >> 3, oct = tid & 7;
        size_t rgl = (size_t)blockIdx.x * 32 + rloc;
        const unsigned short* xr = X + rgl * XPAD;
        float s16[16];
        #pragma unroll
        for (int i = 0; i < 16; ++i) s16[i] = 0.f;
        float ssq = 0.f, fmsum = 0.f, dsum = 0.f;
        #pragma unroll
        for (int ff = 0; ff < 4; ++ff) {
            int f = oct + ff * 8;
            if (f < NF) {
                short8 a = *(const short8*)(xr + f * 16);
                short8 b = *(const short8*)(xr + f * 16 + 8);
                #pragma unroll
                for (int j = 0; j < 8; ++j) {
                    float va = bf2f((unsigned short)a[j]);
                    float vb = bf2f((unsigned short)b[j]);
                    s16[j] += va; s16[8 + j] += vb;
                    ssq += va * va + vb * vb;
                }
                fmsum += fm1v[(size_t)f * B_ROWS + rgl];
            }
        }
        if (oct == 0) {
            short8 d0 = *(const short8*)(xr + 416);
            short8 d1 = *(const short8*)(xr + 424);
            #pragma unroll
            for (int j = 0; j < 8; ++j) dsum += bf2f((unsigned short)d0[j]) * wd_s[j];
            #pragma unroll
            for (int j = 0; j < 5; ++j) dsum += bf2f((unsigned short)d1[j]) * wd_s[8 + j];
        }
        #pragma unroll
        for (int i = 0; i < 16; ++i) {
            s16[i] += __shfl_xor(s16[i], 1, 64);
            s16[i] += __shfl_xor(s16[i], 2, 64);
            s16[i] += __shfl_xor(s16[i], 4, 64);
        }
        ssq += __shfl_xor(ssq, 1, 64);
        ssq += __shfl_xor(ssq, 2, 64);
        ssq += __shfl_xor(ssq, 4, 64);
        fmsum += __shfl_xor(fmsum, 1, 64);
        fmsum += __shfl_xor(fmsum, 2, 64);
        fmsum += __shfl_xor(fmsum, 4, 64);
        if (oct == 0) {
            float sq = 0.f;
            #pragma unroll
            for (int i = 0; i < 16; ++i) sq += s16[i] * s16[i];
            extra_s[rloc] = 0.5f * (sq - ssq) + fmsum + dsum + bd[0];
        }
    }
    __syncthreads();

    // ---------- Phase B: BN2 + dnn dot (R16-proven) ----------
    int lane = tid & 63;
    int wv = tid >> 6;
    bool act = lane < 50;
    int cbx = lane * 8;
    float al[8], bb[8], w3[8];
    #pragma unroll
    for (int j = 0; j < 8; ++j) {
        al[j] = act ? a2s[cbx + j] : 0.f;
        bb[j] = act ? b2s[cbx + j] : 0.f;
        w3[j] = act ? w3s[cbx + j] : 0.f;
    }
    int r0 = blockIdx.x * 32 + wv * 8;
    float bias3 = b3[0];
    for (int t = 0; t < 8; t += 2) {
        int r = r0 + t;
        float acc0 = 0.f, acc1 = 0.f;
        if (act) {
            short8 z0 = *(const short8*)(Z2 + (size_t)r * ZPAD + cbx);
            short8 z1 = *(const short8*)(Z2 + (size_t)(r + 1) * ZPAD + cbx);
            #pragma unroll
            for (int j = 0; j < 8; ++j) {
                acc0 += fmaxf(0.f, al[j] * bf2f((unsigned short)z0[j]) + bb[j]) * w3[j];
                acc1 += fmaxf(0.f, al[j] * bf2f((unsigned short)z1[j]) + bb[j]) * w3[j];
            }
        }
        #pragma unroll
        for (int off = 32; off; off >>= 1) {
            acc0 += __shfl_xor(acc0, off, 64);
            acc1 += __shfl_xor(acc1, off, 64);
        }
        if (lane == 0) out[r] = extra_s[wv * 8 + t] + acc0 + bias3;
        if (lane == 1) out[r + 1] = extra_s[wv * 8 + t + 1] + acc1 + bias3;
    }
}

// =====================================================================
extern "C" void kernel_launch(void* const* d_in, const int* in_sizes, int n_in,
                              void* d_out, int out_size, void* d_ws, size_t ws_size,
                              hipStream_t stream)
{
    const int*   Xcat = (const int*)d_in[0];
    const float* Xd   = (const float*)d_in[1];
    const float* fm1  = (const float*)d_in[2];
    const float* emb  = (const float*)d_in[3];
    const float* Wd   = (const float*)d_in[4];
    const float* bd   = (const float*)d_in[5];
    const float* W1   = (const float*)d_in[6];
    const float* b1   = (const float*)d_in[7];
    const float* g1   = (const float*)d_in[8];
    const float* be1  = (const float*)d_in[9];
    const float* W2   = (const float*)d_in[10];
    const float* b2   = (const float*)d_in[11];
    const float* g2   = (const float*)d_in[12];
    const float* be2  = (const float*)d_in[13];
    const float* W3   = (const float*)d_in[14];
    const float* b3   = (const float*)d_in[15];

    char* ws = (char*)d_ws;
    unsigned short* X    = (unsigned short*)(ws + X_OFF);
    unsigned short* Z1   = (unsigned short*)(ws + Z1_OFF);
    unsigned short* Z2   = (unsigned short*)(ws + Z2_OFF);
    unsigned short* W1s  = (unsigned short*)(ws + W1S_OFF);
    unsigned short* W2s  = (unsigned short*)(ws + W2S_OFF);
    float* fm1v = (float*)(ws + FM1V_OFF);
    float* st   = (float*)(ws + ST_OFF);
    float* out  = (float*)d_out;

    // 1: field-partitioned gather (fm1 XCD-pinned) + W staging + dense cols
    gather_prep<<<1917, 256, 0, stream>>>(Xcat, Xd, fm1, emb, W1, W2,
                                          X, fm1v, W1s, W2s, st);

    // 2: Z1 = X @ W1 + b1, stats1
    gemm_v5<14, XPAD, false><<<256, 512, 0, stream>>>(
        X, W1s, b1, nullptr, nullptr, nullptr, Z1, ZPAD, 1, st, 0, 416);

    // 3: Z2 = relu(bn1(Z1)) @ W2 + b2, stats2
    gemm_v5<13, ZPAD, true><<<256, 512, 0, stream>>>(
        Z1, W2s, b2, st, g1, be1, Z2, ZPAD, 0, st, 832, 1248);

    // 4: out = FM(X) + fm1v + dense + bd + relu(bn2(Z2))·W3 + b3
    final_kernel<<<512, 256, 0, stream>>>(Z2, st, g2, be2, W3, b3,
                                          X, fm1v, Wd, bd, out);
}

// Round 18
// 73.203 us; speedup vs baseline: 1.0679x; 1.0679x over previous
//
#include <hip/hip_runtime.h>
#include <stdint.h>

// ---------------- problem constants ----------------
#define B_ROWS 16384
#define NF 26
#define NV 100000
#define ND 13
#define NH 400
#define XPAD 448     // GEMM1 K padded (14 tiles of 32)
#define ZPAD 416     // GEMM2 K padded (13 tiles of 32)
#define EPS 1e-5f

typedef __attribute__((ext_vector_type(8))) short short8;
typedef __attribute__((ext_vector_type(4))) float f32x4;
typedef __attribute__((ext_vector_type(4))) unsigned int uint4v;

__device__ inline float bf2f(unsigned short u) {
    union { unsigned int i; float f; } v; v.i = (unsigned int)u << 16; return v.f;
}
__device__ inline unsigned short f2bf(float f) {
    union { float f; unsigned int i; } v; v.f = f;
    return (unsigned short)((v.i + 0x7fff + ((v.i >> 16) & 1)) >> 16);
}

// direct global->LDS DMA; one call = 64 lanes x 16B = 1024B at dest base
typedef __attribute__((address_space(1))) const unsigned int g_u32;
typedef __attribute__((address_space(3))) unsigned int l_u32;
__device__ __forceinline__ void gload_lds16(const void* g, void* l) {
    __builtin_amdgcn_global_load_lds((g_u32*)g, (l_u32*)l, 16, 0, 0);
}

// ---------------- ws layout (bytes) ----------------
#define X_OFF    0
#define Z1_OFF   14680064
#define W1S_OFF  28311552
#define W2S_OFF  28712960
#define BASE_OFF 29085696
#define ST_OFF   29151232

// =====================================================================
// gather (blocks 0..1023) + W-staging/stat-zero (blocks 1024..1212)
// (R5/R11/R16-proven, unchanged — 26-deep per-thread MLP is the key)
// =====================================================================
__global__ __launch_bounds__(256) void gather_prep(
    const int* __restrict__ Xcat, const float* __restrict__ Xdense,
    const float* __restrict__ fm1, const float* __restrict__ emb,
    const float* __restrict__ Wd, const float* __restrict__ bd,
    const float* __restrict__ W1, const float* __restrict__ W2,
    unsigned short* __restrict__ X, float* __restrict__ base,
    unsigned short* __restrict__ W1s, unsigned short* __restrict__ W2s,
    float* __restrict__ st)
{
    int tid = threadIdx.x;
    if (blockIdx.x >= 1024) {
        int c = (blockIdx.x - 1024) * 256 + tid;     // 0..48383
        if (c < 256) {
            for (int i = tid; i < 6656; i += 256) st[i] = 0.f;  // 4 replicas
        }
        const float* W; unsigned short* dst; int K; int cc;
        if (c < 25088) { W = W1; dst = W1s; K = 429; cc = c; }
        else           { W = W2; dst = W2s; K = 400; cc = c - 25088; }
        int n  = cc % 448;
        int q  = (cc / 448) & 3;
        int kt = cc / 1792;
        unsigned short o[8];
        #pragma unroll
        for (int j = 0; j < 8; ++j) {
            int k = kt * 32 + q * 8 + j;
            float v = (n < NH && k < K) ? W[(size_t)k * NH + n] : 0.f;
            o[j] = f2bf(v);
        }
        *(uint4v*)(dst + (size_t)cc * 8) = *(uint4v*)o;
        return;
    }
    int r = blockIdx.x * 16 + (tid >> 4);
    int k = tid & 15;
    const int* idxp = Xcat + (size_t)r * NF;
    unsigned short* xrow = X + (size_t)r * XPAD;

    float s = 0.f, ss = 0.f;
    #pragma unroll
    for (int f = 0; f < NF; ++f) {
        int idx = idxp[f];
        float v = emb[((size_t)f * NV + idx) * 16 + k];
        s += v; ss += v * v;
        xrow[f * 16 + k] = f2bf(v);
    }
    float fmsum = fm1[(size_t)k * NV + idxp[k]];
    if (k < NF - 16) fmsum += fm1[(size_t)(k + 16) * NV + idxp[k + 16]];
    float dsum = 0.f;
    if (k < ND) {
        float xd = Xdense[(size_t)r * ND + k];
        dsum = xd * Wd[k];
        xrow[NF * 16 + k] = f2bf(xd);
    }
    xrow[429 + k] = 0;
    if (k < 3) xrow[445 + k] = 0;

    float ix = s * s - ss;
    float rf = fmsum, rd = dsum;
    #pragma unroll
    for (int off = 8; off; off >>= 1) {
        ix += __shfl_xor(ix, off, 16);
        rf += __shfl_xor(rf, off, 16);
        rd += __shfl_xor(rd, off, 16);
    }
    if (k == 0) base[r] = 0.5f * ix + rf + rd + bd[0];
}

// =====================================================================
// gemm_v6: barrier-free per-wave GEMM, 3-deep counted-vmcnt pipeline.
// grid 256 x 512 (1 block/CU by grid). Wave wv=(rg<<2)|w4.
// Per-tile VMEM group G = NFW+2 (W DMAs + 2 A loads) = 9|8.
// Steady-state wait vmcnt(2G): tile kt's ops done, kt+1/kt+2 in flight.
// LDS: 3 bufs x 51,200B + alpha/beta = 156,928B.
// =====================================================================
template<int NT, int LDA, bool APPLY_BN>
__global__ __launch_bounds__(512, 2) void gemm_v6(
    const unsigned short* __restrict__ A,
    const unsigned short* __restrict__ Wst,
    const float* __restrict__ bias,
    const float* __restrict__ st_all,
    const float* __restrict__ g, const float* __restrict__ be,
    unsigned short* __restrict__ Z, int ldz, int padZ,
    float* __restrict__ st_out, int sumOff, int sqOff)
{
    __shared__ __align__(16) unsigned short slices[76800];  // 3 bufs x 25600
    __shared__ float alpha_s[416], beta_s[416];

    const int tid = threadIdx.x, bid = blockIdx.x;
    const int lane = tid & 63, wv = tid >> 6;
    const int rg = wv >> 2, w4 = wv & 3;
    const int l15 = lane & 15, qh = lane >> 4;
    const int cb = (w4 == 0) ? 0 : (112 + (w4 - 1) * 96);
    const int NFW = (w4 == 0) ? 7 : 6;
    const int soff = rg * 12800 + ((w4 == 0) ? 0 : (3584 + (w4 - 1) * 3072));
    const int arowA = bid * 64 + rg * 32 + l15;
    const int arowB = arowA + 16;

    if constexpr (APPLY_BN) {
        if (tid < 416) {
            int c = tid;
            float a = 0.f, b = 0.f;
            if (c < NH) {
                float gs = 0.f, gq = 0.f;
                #pragma unroll
                for (int cp = 0; cp < 4; ++cp) {
                    gs += st_all[cp * 1664 + c];
                    gq += st_all[cp * 1664 + 416 + c];
                }
                float mean = gs * (1.f / 16384.f);
                float var  = gq * (1.f / 16384.f) - mean * mean;
                a = g[c] * rsqrtf(var + EPS);
                b = be[c] - mean * a;
            }
            alpha_s[c] = a; beta_s[c] = b;
        }
        __syncthreads();
    }

    f32x4 acc0[7], acc1[7];
    #pragma unroll
    for (int i = 0; i < 7; ++i) { acc0[i] = f32x4{0,0,0,0}; acc1[i] = f32x4{0,0,0,0}; }

    auto stageW = [&](int kt, int buf) {
        unsigned short* sl = slices + buf * 25600 + soff;
        #pragma unroll
        for (int i = 0; i < 7; ++i) if (i < NFW) {
            int ci = (kt * 4 + qh) * 448 + cb + i * 16 + l15;
            gload_lds16(Wst + (size_t)ci * 8, sl + i * 512);
        }
    };
    auto ldA = [&](int kt, short8& a, short8& b) {
        a = *(const short8*)(A + (size_t)arowA * LDA + kt * 32 + qh * 8);
        b = *(const short8*)(A + (size_t)arowB * LDA + kt * 32 + qh * 8);
    };
    // waitTiles = # of YOUNGER tile-groups still allowed in flight
    auto waitV = [&](int waitTiles) {
        if (waitTiles == 2) {
            if (w4 == 0) asm volatile("s_waitcnt vmcnt(18)" ::: "memory");
            else         asm volatile("s_waitcnt vmcnt(16)" ::: "memory");
        } else if (waitTiles == 1) {
            if (w4 == 0) asm volatile("s_waitcnt vmcnt(9)" ::: "memory");
            else         asm volatile("s_waitcnt vmcnt(8)" ::: "memory");
        } else {
            asm volatile("s_waitcnt vmcnt(0)" ::: "memory");
        }
        __builtin_amdgcn_sched_barrier(0);
    };
    auto waitlg = [&]() {
        asm volatile("s_waitcnt lgkmcnt(0)" ::: "memory");
        __builtin_amdgcn_sched_barrier(0);
    };

    // phase: consume tile kt from buf; optionally issue tile kt+3 into buf.
    auto phase = [&](int kt, int buf, int waitTiles, bool issue,
                     short8& afA, short8& afB) {
        waitV(waitTiles);
        const unsigned short* sl = slices + buf * 25600 + soff;
        short8 bf[7];
        #pragma unroll
        for (int i = 0; i < 7; ++i) if (i < NFW)
            bf[i] = *(const short8*)(sl + i * 512 + lane * 8);
        short8 aA = afA, aB = afB;
        waitlg();                            // ds_reads retired -> buf reusable
        if (issue) { stageW(kt + 3, buf); ldA(kt + 3, afA, afB); }
        if constexpr (APPLY_BN) {
            const int k0 = kt * 32 + qh * 8;
            #pragma unroll
            for (int j = 0; j < 8; ++j) {
                float al = alpha_s[k0 + j], bt = beta_s[k0 + j];
                aA[j] = (short)f2bf(fmaxf(0.f, al * bf2f((unsigned short)aA[j]) + bt));
                aB[j] = (short)f2bf(fmaxf(0.f, al * bf2f((unsigned short)aB[j]) + bt));
            }
        }
        #pragma unroll
        for (int i = 0; i < 7; ++i) if (i < NFW) {
            acc0[i] = __builtin_amdgcn_mfma_f32_16x16x32_bf16(aA, bf[i], acc0[i], 0, 0, 0);
            acc1[i] = __builtin_amdgcn_mfma_f32_16x16x32_bf16(aB, bf[i], acc1[i], 0, 0, 0);
        }
    };

    short8 aA0, aB0, aA1, aB1, aA2, aB2;
    stageW(0, 0); ldA(0, aA0, aB0);          // prologue: tiles 0,1,2 in flight
    stageW(1, 1); ldA(1, aA1, aB1);
    stageW(2, 2); ldA(2, aA2, aB2);

    int kt = 0;
    for (; kt + 5 < NT; kt += 3) {           // NT=14: kt=0,3,6 ; NT=13: 0,3,6
        phase(kt,     0, 2, true, aA0, aB0);
        phase(kt + 1, 1, 2, true, aA1, aB1);
        phase(kt + 2, 2, 2, true, aA2, aB2);
    }
    if constexpr (NT == 14) {                // tail: tiles 9..13
        phase(9,  0, 2, true,  aA0, aB0);    // issues 12 -> buf0
        phase(10, 1, 2, true,  aA1, aB1);    // issues 13 -> buf1
        phase(11, 2, 2, false, aA2, aB2);
        phase(12, 0, 1, false, aA0, aB0);
        phase(13, 1, 0, false, aA1, aB1);
    } else {                                 // NT == 13: tail tiles 9..12
        phase(9,  0, 2, true,  aA0, aB0);    // issues 12 -> buf0
        phase(10, 1, 2, false, aA1, aB1);
        phase(11, 2, 1, false, aA2, aB2);
        phase(12, 0, 0, false, aA0, aB0);
    }

    // ---- epilogue: +bias, bf16 store, per-wave stats -> replica atomics ----
    float* stc = st_out + (bid & 3) * 1664;
    #pragma unroll
    for (int i = 0; i < 7; ++i) if (i < NFW) {
        int col = cb + i * 16 + l15;
        float bv = bias[col];
        float ps = 0.f, pq = 0.f;
        #pragma unroll
        for (int q = 0; q < 4; ++q) {
            float v0 = acc0[i][q] + bv;
            float v1 = acc1[i][q] + bv;
            Z[(size_t)(bid * 64 + rg * 32 + qh * 4 + q) * ldz + col] = f2bf(v0);
            Z[(size_t)(bid * 64 + rg * 32 + 16 + qh * 4 + q) * ldz + col] = f2bf(v1);
            ps += v0 + v1; pq += v0 * v0 + v1 * v1;
        }
        ps += __shfl_xor(ps, 16, 64); ps += __shfl_xor(ps, 32, 64);
        pq += __shfl_xor(pq, 16, 64); pq += __shfl_xor(pq, 32, 64);
        if (qh == 0) {
            atomicAdd(&stc[sumOff + col], ps);
            atomicAdd(&stc[sqOff + col], pq);
        }
    }
    if (padZ && w4 == 3) {   // zero cols 400..415 (this rg's 32 rows)
        #pragma unroll
        for (int rr = 0; rr < 8; ++rr)
            Z[(size_t)(bid * 64 + rg * 32 + rr * 4 + qh) * ldz + 400 + l15] = 0;
    }
}

// =====================================================================
// final: BN2 from replicas, then out[r] = base[r] + relu(.)·W3 + b3
// (R16-proven, unchanged)
// =====================================================================
__global__ __launch_bounds__(256) void final_kernel(
    const unsigned short* __restrict__ Z2,
    const float* __restrict__ st_all,
    const float* __restrict__ g2, const float* __restrict__ be2,
    const float* __restrict__ W3, const float* __restrict__ b3,
    const float* __restrict__ base, float* __restrict__ out)
{
    __shared__ float a2s[NH], b2s[NH], w3s[NH];
    int tid = threadIdx.x;
    for (int c = tid; c < NH; c += 256) {
        float gs = 0.f, gq = 0.f;
        #pragma unroll
        for (int cp = 0; cp < 4; ++cp) {
            gs += st_all[cp * 1664 + 832 + c];
            gq += st_all[cp * 1664 + 1248 + c];
        }
        float mean = gs * (1.f / 16384.f);
        float var  = gq * (1.f / 16384.f) - mean * mean;
        float a = g2[c] * rsqrtf(var + EPS);
        a2s[c] = a;
        b2s[c] = be2[c] - mean * a;
        w3s[c] = W3[c];
    }
    __syncthreads();
    int lane = tid & 63;
    int wv = tid >> 6;
    bool act = lane < 50;
    int cb = lane * 8;
    float al[8], bb[8], w3[8];
    #pragma unroll
    for (int j = 0; j < 8; ++j) {
        al[j] = act ? a2s[cb + j] : 0.f;
        bb[j] = act ? b2s[cb + j] : 0.f;
        w3[j] = act ? w3s[cb + j] : 0.f;
    }
    int r0 = blockIdx.x * 32 + wv * 8;
    float bias3 = b3[0];
    for (int t = 0; t < 8; t += 2) {
        int r = r0 + t;
        float acc0 = 0.f, acc1 = 0.f;
        if (act) {
            short8 z0 = *(const short8*)(Z2 + (size_t)r * ZPAD + cb);
            short8 z1 = *(const short8*)(Z2 + (size_t)(r + 1) * ZPAD + cb);
            #pragma unroll
            for (int j = 0; j < 8; ++j) {
                acc0 += fmaxf(0.f, al[j] * bf2f((unsigned short)z0[j]) + bb[j]) * w3[j];
                acc1 += fmaxf(0.f, al[j] * bf2f((unsigned short)z1[j]) + bb[j]) * w3[j];
            }
        }
        #pragma unroll
        for (int off = 32; off; off >>= 1) {
            acc0 += __shfl_xor(acc0, off, 64);
            acc1 += __shfl_xor(acc1, off, 64);
        }
        if (lane == 0) out[r] = base[r] + acc0 + bias3;
        if (lane == 1) out[r + 1] = base[r + 1] + acc1 + bias3;
    }
}

// =====================================================================
extern "C" void kernel_launch(void* const* d_in, const int* in_sizes, int n_in,
                              void* d_out, int out_size, void* d_ws, size_t ws_size,
                              hipStream_t stream)
{
    const int*   Xcat = (const int*)d_in[0];
    const float* Xd   = (const float*)d_in[1];
    const float* fm1  = (const float*)d_in[2];
    const float* emb  = (const float*)d_in[3];
    const float* Wd   = (const float*)d_in[4];
    const float* bd   = (const float*)d_in[5];
    const float* W1   = (const float*)d_in[6];
    const float* b1   = (const float*)d_in[7];
    const float* g1   = (const float*)d_in[8];
    const float* be1  = (const float*)d_in[9];
    const float* W2   = (const float*)d_in[10];
    const float* b2   = (const float*)d_in[11];
    const float* g2   = (const float*)d_in[12];
    const float* be2  = (const float*)d_in[13];
    const float* W3   = (const float*)d_in[14];
    const float* b3   = (const float*)d_in[15];

    char* ws = (char*)d_ws;
    unsigned short* X   = (unsigned short*)(ws + X_OFF);
    unsigned short* Z1  = (unsigned short*)(ws + Z1_OFF);
    unsigned short* Z2  = X;   // X dead after GEMM1
    unsigned short* W1s = (unsigned short*)(ws + W1S_OFF);
    unsigned short* W2s = (unsigned short*)(ws + W2S_OFF);
    float* base = (float*)(ws + BASE_OFF);
    float* st   = (float*)(ws + ST_OFF);
    float* out  = (float*)d_out;

    // 1: gather + W staging + 4-replica stat zero
    gather_prep<<<1213, 256, 0, stream>>>(Xcat, Xd, fm1, emb, Wd, bd, W1, W2,
                                          X, base, W1s, W2s, st);

    // 2: Z1 = X @ W1 + b1, stats1 (3-deep pipelined barrier-free GEMM)
    gemm_v6<14, XPAD, false><<<256, 512, 0, stream>>>(
        X, W1s, b1, nullptr, nullptr, nullptr, Z1, ZPAD, 1, st, 0, 416);

    // 3: Z2 = relu(bn1(Z1)) @ W2 + b2, stats2
    gemm_v6<13, ZPAD, true><<<256, 512, 0, stream>>>(
        Z1, W2s, b2, st, g1, be1, Z2, ZPAD, 0, st, 832, 1248);

    // 4: out = base + relu(bn2(Z2))·W3 + b3
    final_kernel<<<512, 256, 0, stream>>>(Z2, st, g2, be2, W3, b3, base, out);
}